// Round 3
// baseline (107.548 us; speedup 1.0000x reference)
//
#include <hip/hip_runtime.h>

// EMA: y[t] = a*x[t] + (1-a)*y[t-1], y_prev init = x[0]  (so y[0] == x[0]).
// (1-a)=0.7 decays below tolerance in ~30 steps (0.7^31 ~ 1.6e-5 vs 2e-2
// threshold), so each output depends only on the trailing K=32 inputs.
// Each thread warm-starts its carry from a K-element halo, then runs the
// exact recurrence over its own R=16-element segment. Segments whose halo
// reaches t=0 clamp to the exact init y[0]=x[0].
//
// R1/R2 changes vs R0: TILE 8192->4096 (LDS 34->17 KB, 4->8 blocks/CU = 100%
// wave occupancy), K 64->32 (halve warm-up), non-temporal stores (keep the
// input resident in the 256 MB L3 instead of letting the output evict it).
// R2: use clang ext_vector_type for the NT store (float4* rejected).

#define EMA_ALPHA 0.3f
#define EMA_BETA  0.7f
#define BLOCK 256
#define R     16                 // outputs per thread
#define TILE  (BLOCK * R)        // 4096 elements per block
#define K     32                 // warm-up halo length

typedef float floatx4 __attribute__((ext_vector_type(4)));

// skew: +1 word every 32 keeps wave64 LDS access at 2 lanes/bank (free, m136).
__device__ __forceinline__ int skew(int i) { return i + (i >> 5); }

__global__ __launch_bounds__(BLOCK) void ema_kernel(
    const float* __restrict__ x, float* __restrict__ y,
    int T, int tilesPerRow) {
  __shared__ float lds[TILE + K + ((TILE + K) >> 5) + 1];

  const int tid      = threadIdx.x;
  const int row      = blockIdx.x / tilesPerRow;
  const int tile     = blockIdx.x % tilesPerRow;
  const int tile_t0  = tile * TILE;
  const float* xrow  = x + (size_t)row * (size_t)T;
  float*       yrow  = y + (size_t)row * (size_t)T;

  // ---- Phase 1: coalesced global -> LDS (tile + left halo), float4 ----
  // LDS position p corresponds to global t = tile_t0 - K + p.
  const int NV = (TILE + K) / 4;  // 1032 float4s
  for (int p4 = tid; p4 < NV; p4 += BLOCK) {
    const int p = p4 * 4;
    const int t = tile_t0 - K + p;           // multiple of 4
    if (t >= 0) {                            // t<0 halo only in first tile; never read
      const float4 v = *reinterpret_cast<const float4*>(xrow + t);
      lds[skew(p    )] = v.x;
      lds[skew(p + 1)] = v.y;
      lds[skew(p + 2)] = v.z;
      lds[skew(p + 3)] = v.w;
    }
  }
  __syncthreads();

  // ---- Phase 2: warm-up carry over [s, t0) ----
  const int t0 = tile_t0 + tid * R;          // this thread's first output index
  float c;
  if (t0 - K > 0) {
    // steady state: fixed K-1 step warm-up (compiler fully unrolls)
    const int ps = tid * R;                  // LDS position of t0-K
    c = lds[skew(ps)];
#pragma unroll
    for (int it = 1; it < K; ++it) {
      c = fmaf(EMA_ALPHA, lds[skew(ps + it)], EMA_BETA * c);
    }
  } else {
    // first threads of each row's first tile: clamp halo to t=0 (exact)
    const int s  = 0;
    int ps = s - tile_t0 + K;                // == K - tile_t0, tile==0 -> K... wait tile_t0==0 here
    ps = K + s - tile_t0 - K + 0;            // simplify below
    ps = s + K - tile_t0;                    // LDS position of s (tile_t0==0 -> ps=K? no)
    // For tile 0, LDS position of global t is t + K.
    ps = K;                                  // position of t=0... actually t=0 -> p = 0 - (0-K) = K
    c = lds[skew(ps)];                       // exact x[0]
    const int nwu = t0 - 1;                  // steps from t=0 up to t0-1
    for (int it = 0; it < nwu; ++it) {
      ++ps;
      c = fmaf(EMA_ALPHA, lds[skew(ps)], EMA_BETA * c);
    }
  }

  // ---- Phase 3: exact scan of own segment, NT vector store ----
  const int p0 = K + tid * R;
  floatx4 o[R / 4];
#pragma unroll
  for (int j = 0; j < R; ++j) {
    c = fmaf(EMA_ALPHA, lds[skew(p0 + j)], EMA_BETA * c);
    reinterpret_cast<float*>(o)[j] = c;
  }
#pragma unroll
  for (int q = 0; q < R / 4; ++q) {
    __builtin_nontemporal_store(o[q],
        reinterpret_cast<floatx4*>(yrow + t0 + q * 4));
  }
}

extern "C" void kernel_launch(void* const* d_in, const int* in_sizes, int n_in,
                              void* d_out, int out_size, void* d_ws, size_t ws_size,
                              hipStream_t stream) {
  const float* x = (const float*)d_in[0];
  float* y = (float*)d_out;

  const int T = 65536;                 // per problem spec
  const int B = in_sizes[0] / T;       // 512
  const int tilesPerRow = T / TILE;    // 16
  const int grid = B * tilesPerRow;    // 8192 blocks

  ema_kernel<<<grid, BLOCK, 0, stream>>>(x, y, T, tilesPerRow);
}

// Round 4
// 45.634 us; speedup vs baseline: 2.3568x; 2.3568x over previous
//
#include <hip/hip_runtime.h>

// EMA: y[t] = a*x[t] + (1-a)*y[t-1], y_prev init = x[0]  (so y[0] == x[0]).
// (1-a)=0.7 decays below tolerance in ~30 steps (0.7^31 ~ 1.6e-5 vs 2e-2
// threshold), so each output depends only on the trailing K=32 inputs.
// Each thread warm-starts its carry from a K-element halo, then runs the
// exact recurrence over its own R=16-element segment. Segments whose halo
// reaches t=0 clamp to the exact init y[0]=x[0].
//
// R3: R0's proven structure (LDS write-back + coalesced float4 stores,
// WRITE_SIZE=128MB, 0 bank conflicts) + R1's occupancy win (TILE=4096,
// LDS 17KB -> 8 blocks/CU) + K=32 + NT on the *coalesced* stores only.
// R2's direct scattered NT stores caused 2x write amplification + scratch
// spill (VGPR=12) -- reverted.

#define EMA_ALPHA 0.3f
#define EMA_BETA  0.7f
#define BLOCK 256
#define R     16                 // outputs per thread
#define TILE  (BLOCK * R)        // 4096 elements per block
#define K     32                 // warm-up halo length

typedef float floatx4 __attribute__((ext_vector_type(4)));

// skew: +1 word every 32 keeps wave64 LDS access at <=2 lanes/bank (free, m136).
__device__ __forceinline__ int skew(int i) { return i + (i >> 5); }

__global__ __launch_bounds__(BLOCK) void ema_kernel(
    const float* __restrict__ x, float* __restrict__ y,
    int T, int tilesPerRow) {
  __shared__ float lds[TILE + K + ((TILE + K) >> 5) + 1];

  const int tid      = threadIdx.x;
  const int row      = blockIdx.x / tilesPerRow;
  const int tile     = blockIdx.x % tilesPerRow;
  const int tile_t0  = tile * TILE;
  const float* xrow  = x + (size_t)row * (size_t)T;
  float*       yrow  = y + (size_t)row * (size_t)T;

  // ---- Phase 1: coalesced global -> LDS (tile + left halo), float4 ----
  // LDS position p corresponds to global t = tile_t0 - K + p.
  const int NV = (TILE + K) / 4;  // 1032 float4s
  for (int p4 = tid; p4 < NV; p4 += BLOCK) {
    const int p = p4 * 4;
    const int t = tile_t0 - K + p;           // multiple of 4
    if (t >= 0) {                            // t<0 halo only in first tile; never read
      const float4 v = *reinterpret_cast<const float4*>(xrow + t);
      lds[skew(p    )] = v.x;
      lds[skew(p + 1)] = v.y;
      lds[skew(p + 2)] = v.z;
      lds[skew(p + 3)] = v.w;
    }
  }
  __syncthreads();

  // ---- Phase 2: warm-up carry over [s, t0) ----
  const int t0 = tile_t0 + tid * R;          // this thread's first output index
  float c;
  if (t0 - K > 0) {
    // steady state: fixed K-1 step warm-up (fully unrolled)
    const int ps = tid * R;                  // LDS position of t0-K
    c = lds[skew(ps)];
#pragma unroll
    for (int it = 1; it < K; ++it) {
      c = fmaf(EMA_ALPHA, lds[skew(ps + it)], EMA_BETA * c);
    }
  } else {
    // tile 0, tid<=2: clamp halo to t=0 (exact). LDS pos of global t is t+K.
    int ps = K;
    c = lds[skew(ps)];                       // exact x[0]
    const int nwu = t0 - 1;                  // steps over t=1..t0-1
    for (int it = 0; it < nwu; ++it) {
      ++ps;
      c = fmaf(EMA_ALPHA, lds[skew(ps)], EMA_BETA * c);
    }
  }
  __syncthreads();   // all warm-ups read pristine tile before in-place writes

  // ---- Phase 3: exact in-place scan of own segment ----
  const int p0 = K + tid * R;
#pragma unroll
  for (int j = 0; j < R; ++j) {
    c = fmaf(EMA_ALPHA, lds[skew(p0 + j)], EMA_BETA * c);
    lds[skew(p0 + j)] = c;
  }
  __syncthreads();

  // ---- Phase 4: coalesced LDS -> global NT store, float4 ----
  for (int p4 = tid; p4 < TILE / 4; p4 += BLOCK) {
    const int p = p4 * 4;
    floatx4 v;
    v.x = lds[skew(K + p    )];
    v.y = lds[skew(K + p + 1)];
    v.z = lds[skew(K + p + 2)];
    v.w = lds[skew(K + p + 3)];
    __builtin_nontemporal_store(v,
        reinterpret_cast<floatx4*>(yrow + tile_t0 + p));
  }
}

extern "C" void kernel_launch(void* const* d_in, const int* in_sizes, int n_in,
                              void* d_out, int out_size, void* d_ws, size_t ws_size,
                              hipStream_t stream) {
  const float* x = (const float*)d_in[0];
  float* y = (float*)d_out;

  const int T = 65536;                 // per problem spec
  const int B = in_sizes[0] / T;       // 512
  const int tilesPerRow = T / TILE;    // 16
  const int grid = B * tilesPerRow;    // 8192 blocks

  ema_kernel<<<grid, BLOCK, 0, stream>>>(x, y, T, tilesPerRow);
}